// Round 2
// baseline (9572.426 us; speedup 1.0000x reference)
//
#include <hip/hip_runtime.h>
#include <hip/hip_bf16.h>
#include <math.h>

// EventTransformer on MI355X — round 1: fp32 compute, bf16 qkv staging,
// chunked FF to fit workspace in ~236 MB. Packed-token layout:
// rows 0..N-1 = DOM tokens (input order), rows N..N+B-1 = CLS tokens.

#define D_INPUT  128
#define DM       256
#define NHEADS   4
#define HDIM     64
#define NLAYERS  4
#define DFF      1024
#define BEV      128
#define LNEPS    1e-5f

__device__ inline float bf2f(unsigned short u) {
    union { unsigned int i; float f; } c; c.i = ((unsigned int)u) << 16; return c.f;
}
__device__ inline unsigned short f2bf(float x) {
    unsigned int xi = __float_as_uint(x);
    unsigned int r  = xi + 0x7FFFu + ((xi >> 16) & 1u);   // RNE
    return (unsigned short)(r >> 16);
}

// ---------------- prep kernels ----------------

__global__ void zero_counts_kernel(int* counts) { counts[threadIdx.x] = 0; }

__global__ void count_kernel(const int* __restrict__ idx, int* __restrict__ counts, int N) {
    int i = blockIdx.x * blockDim.x + threadIdx.x;
    if (i < N) atomicAdd(&counts[idx[i]], 1);
}

__global__ void scan_kernel(const int* __restrict__ counts, int* __restrict__ starts) {
    if (threadIdx.x == 0) {
        int s = 0;
        for (int b = 0; b < BEV; ++b) { starts[b] = s; s += counts[b]; }
    }
}

__global__ void beacon_kernel(float* out, int n, float v) {
    int i = blockIdx.x * blockDim.x + threadIdx.x;
    if (i < n) out[i] = v;
}

// We (256 x 384) = [in_proj_w | geo_proj_w[:, :252] | 0]; be = in_b + geo_b.
__global__ void prep_w_kernel(const float* __restrict__ win, const float* __restrict__ wgeo,
                              const float* __restrict__ bin, const float* __restrict__ bgeo,
                              float* __restrict__ We, float* __restrict__ be) {
    int i = blockIdx.x * blockDim.x + threadIdx.x;
    if (i < 256 * 384) {
        int o = i / 384, k = i % 384;
        float v = 0.f;
        if (k < 128)      v = win[o * 128 + k];
        else if (k < 380) v = wgeo[o * 256 + (k - 128)];
        We[i] = v;
    }
    if (i < 256) be[i] = bin[i] + bgeo[i];
}

// A (N x 384) = [dom_embeddings | pos_enc (252) | 0]. posenc idx = axis*84+band*2+{sin,cos}.
__global__ void prep_a_kernel(const float* __restrict__ emb, const float* __restrict__ geo,
                              float* __restrict__ A, int N) {
    size_t i = (size_t)blockIdx.x * blockDim.x + threadIdx.x;
    if (i >= (size_t)N * 384) return;
    int k = (int)(i % 384);
    size_t r = i / 384;
    float v = 0.f;
    if (k < 128) {
        v = emb[r * 128 + k];
    } else if (k < 380) {
        int rem  = k - 128;
        int axis = rem / 84;
        int r2   = rem % 84;
        int band = r2 >> 1;
        int sc   = r2 & 1;
        float freq = expf((float)band * (2.3025850929940457f / 41.0f)); // 10^(band/41)
        float ang  = (6.283185307179586f * geo[r * 3 + axis]) * freq;
        v = sc ? cosf(ang) : sinf(ang);
    }
    A[i] = v;
}

__global__ void cls_kernel(const float* __restrict__ cls, float* __restrict__ h, int N) {
    h[(size_t)(N + blockIdx.x) * DM + threadIdx.x] = cls[threadIdx.x];
}

// ---------------- layernorm: one wave per row of 256 ----------------

__global__ __launch_bounds__(256) void ln_kernel(const float* __restrict__ x,
                                                 const float* __restrict__ w,
                                                 const float* __restrict__ b,
                                                 float* __restrict__ y, int T) {
    int row  = blockIdx.x * 4 + (threadIdx.x >> 6);
    int lane = threadIdx.x & 63;
    if (row >= T) return;
    float4 v = ((const float4*)(x + (size_t)row * DM))[lane];
    float s = v.x + v.y + v.z + v.w;
    #pragma unroll
    for (int off = 32; off > 0; off >>= 1) s += __shfl_xor(s, off);
    float mean = s * (1.0f / 256.0f);
    float dx = v.x - mean, dy = v.y - mean, dz = v.z - mean, dw = v.w - mean;
    float ss = dx * dx + dy * dy + dz * dz + dw * dw;
    #pragma unroll
    for (int off = 32; off > 0; off >>= 1) ss += __shfl_xor(ss, off);
    float inv = rsqrtf(ss * (1.0f / 256.0f) + LNEPS);
    float4 wv = ((const float4*)w)[lane];
    float4 bv = ((const float4*)b)[lane];
    float4 o;
    o.x = dx * inv * wv.x + bv.x;
    o.y = dy * inv * wv.y + bv.y;
    o.z = dz * inv * wv.z + bv.z;
    o.w = dw * inv * wv.w + bv.w;
    ((float4*)(y + (size_t)row * DM))[lane] = o;
}

// ---------------- fp32 SGEMM: C[T,No] = A[T,K] @ W[No,K]^T + bias ----------------
// TC = float (flags: 1 relu, 2 residual-add) or ushort (bf16 store, bias only).
// 128x128 block tile, 16 K-tile, 256 threads, 8x8 microtile.

template <typename TC>
__global__ __launch_bounds__(256) void gemm_kernel(const float* __restrict__ A,
                                                   const float* __restrict__ W,
                                                   const float* __restrict__ bias,
                                                   TC* __restrict__ C,
                                                   int K, int No, int flags) {
    __shared__ float As[16][132];
    __shared__ float Bs[16][132];
    const int m0 = blockIdx.y * 128;
    const int n0 = blockIdx.x * 128;
    const int tid = threadIdx.x;
    const int tx = tid & 15, ty = tid >> 4;
    const int lr = tid >> 2;
    const int lc = tid & 3;

    float acc[8][8];
    #pragma unroll
    for (int i = 0; i < 8; ++i)
        #pragma unroll
        for (int j = 0; j < 8; ++j) acc[i][j] = 0.f;

    const float* Ap = A + (size_t)(m0 + lr) * K + lc * 4;
    const float* Wp = W + (size_t)(n0 + lr) * K + lc * 4;
    const size_t a64 = (size_t)64 * K;

    for (int kt = 0; kt < K; kt += 16) {
        float4 a0 = *(const float4*)(Ap + kt);
        float4 a1 = *(const float4*)(Ap + kt + a64);
        float4 b0 = *(const float4*)(Wp + kt);
        float4 b1 = *(const float4*)(Wp + kt + a64);
        __syncthreads();
        As[lc * 4 + 0][lr] = a0.x;  As[lc * 4 + 1][lr] = a0.y;
        As[lc * 4 + 2][lr] = a0.z;  As[lc * 4 + 3][lr] = a0.w;
        As[lc * 4 + 0][64 + lr] = a1.x;  As[lc * 4 + 1][64 + lr] = a1.y;
        As[lc * 4 + 2][64 + lr] = a1.z;  As[lc * 4 + 3][64 + lr] = a1.w;
        Bs[lc * 4 + 0][lr] = b0.x;  Bs[lc * 4 + 1][lr] = b0.y;
        Bs[lc * 4 + 2][lr] = b0.z;  Bs[lc * 4 + 3][lr] = b0.w;
        Bs[lc * 4 + 0][64 + lr] = b1.x;  Bs[lc * 4 + 1][64 + lr] = b1.y;
        Bs[lc * 4 + 2][64 + lr] = b1.z;  Bs[lc * 4 + 3][64 + lr] = b1.w;
        __syncthreads();
        #pragma unroll
        for (int kk = 0; kk < 16; ++kk) {
            float4 av0 = *(const float4*)&As[kk][ty * 4];
            float4 av1 = *(const float4*)&As[kk][64 + ty * 4];
            float4 bv0 = *(const float4*)&Bs[kk][tx * 4];
            float4 bv1 = *(const float4*)&Bs[kk][64 + tx * 4];
            float a[8] = {av0.x, av0.y, av0.z, av0.w, av1.x, av1.y, av1.z, av1.w};
            float b[8] = {bv0.x, bv0.y, bv0.z, bv0.w, bv1.x, bv1.y, bv1.z, bv1.w};
            #pragma unroll
            for (int i = 0; i < 8; ++i)
                #pragma unroll
                for (int j = 0; j < 8; ++j)
                    acc[i][j] = fmaf(a[i], b[j], acc[i][j]);
        }
    }

    #pragma unroll
    for (int i = 0; i < 8; ++i) {
        int row = m0 + ((i >> 2) * 64) + ty * 4 + (i & 3);
        #pragma unroll
        for (int j2 = 0; j2 < 2; ++j2) {
            int col = n0 + j2 * 64 + tx * 4;
            float4 bb = *(const float4*)&bias[col];
            float cx = acc[i][j2 * 4 + 0] + bb.x;
            float cy = acc[i][j2 * 4 + 1] + bb.y;
            float cz = acc[i][j2 * 4 + 2] + bb.z;
            float cw = acc[i][j2 * 4 + 3] + bb.w;
            if constexpr (sizeof(TC) == 4) {
                float* cp = (float*)C + (size_t)row * No + col;
                if (flags & 2) {
                    float4 old = *(const float4*)cp;
                    cx += old.x; cy += old.y; cz += old.z; cw += old.w;
                }
                if (flags & 1) {
                    cx = fmaxf(cx, 0.f); cy = fmaxf(cy, 0.f);
                    cz = fmaxf(cz, 0.f); cw = fmaxf(cw, 0.f);
                }
                float4 c = {cx, cy, cz, cw};
                *(float4*)cp = c;
            } else {
                ushort4 u;
                u.x = f2bf(cx); u.y = f2bf(cy); u.z = f2bf(cz); u.w = f2bf(cw);
                *(ushort4*)((unsigned short*)C + (size_t)row * No + col) = u;
            }
        }
    }
}

// ---------------- attention: thread-per-query flash over bf16 qkv ----------------
// qkv: (T, 768) bf16 packed [q|k|v]. Row for (b,s): s==0 -> N+b else starts[b]+s-1.

#define CK 64

__global__ __launch_bounds__(256) void attn_kernel(const unsigned short* __restrict__ qkv,
                                                   const int* __restrict__ counts,
                                                   const int* __restrict__ starts,
                                                   float* __restrict__ out, int N) {
    const int b  = blockIdx.x >> 2;
    const int hh = blockIdx.x & 3;
    const int Sb = counts[b] + 1;
    const int qbase = blockIdx.y * 256;
    if (qbase >= Sb) return;
    __shared__ float Ks[CK][HDIM];
    __shared__ float Vs[CK][HDIM];
    const int t = threadIdx.x;
    const int start = starts[b];
    const int qi = qbase + t;
    const bool qvalid = qi < Sb;
    const size_t qrow = qvalid ? (qi == 0 ? (size_t)(N + b) : (size_t)(start + qi - 1))
                               : (size_t)(N + b);
    const unsigned short* qp = qkv + qrow * 768 + hh * HDIM;

    float q[HDIM];
    #pragma unroll
    for (int d = 0; d < HDIM; d += 4) {
        ushort4 u = *(const ushort4*)(qp + d);
        q[d + 0] = bf2f(u.x) * 0.125f;  q[d + 1] = bf2f(u.y) * 0.125f;
        q[d + 2] = bf2f(u.z) * 0.125f;  q[d + 3] = bf2f(u.w) * 0.125f;
    }
    float acc[HDIM];
    #pragma unroll
    for (int d = 0; d < HDIM; ++d) acc[d] = 0.f;
    float m = -1e30f, l = 0.f;

    const int kk = t >> 2;
    const int kp = t & 3;

    for (int kbase = 0; kbase < Sb; kbase += CK) {
        int nk = Sb - kbase; if (nk > CK) nk = CK;
        __syncthreads();
        if (kk < nk) {
            int ki = kbase + kk;
            size_t krow = (ki == 0) ? (size_t)(N + b) : (size_t)(start + ki - 1);
            const unsigned short* kpp = qkv + krow * 768 + 256 + hh * HDIM + kp * 16;
            const unsigned short* vpp = qkv + krow * 768 + 512 + hh * HDIM + kp * 16;
            #pragma unroll
            for (int u2 = 0; u2 < 4; ++u2) {
                ushort4 uk = *(const ushort4*)(kpp + u2 * 4);
                ushort4 uv = *(const ushort4*)(vpp + u2 * 4);
                float4 fk = {bf2f(uk.x), bf2f(uk.y), bf2f(uk.z), bf2f(uk.w)};
                float4 fv = {bf2f(uv.x), bf2f(uv.y), bf2f(uv.z), bf2f(uv.w)};
                *(float4*)&Ks[kk][kp * 16 + u2 * 4] = fk;
                *(float4*)&Vs[kk][kp * 16 + u2 * 4] = fv;
            }
        }
        __syncthreads();
        if (qvalid) {
            for (int k = 0; k < nk; ++k) {
                float s = 0.f;
                #pragma unroll
                for (int d = 0; d < HDIM; d += 4) {
                    float4 kv = *(const float4*)&Ks[k][d];
                    s = fmaf(q[d + 0], kv.x, s); s = fmaf(q[d + 1], kv.y, s);
                    s = fmaf(q[d + 2], kv.z, s); s = fmaf(q[d + 3], kv.w, s);
                }
                if (s > m) {
                    float sc = __expf(m - s);
                    l *= sc;
                    #pragma unroll
                    for (int d = 0; d < HDIM; ++d) acc[d] *= sc;
                    m = s;
                }
                float p = __expf(s - m);
                l += p;
                #pragma unroll
                for (int d = 0; d < HDIM; d += 4) {
                    float4 vv = *(const float4*)&Vs[k][d];
                    acc[d + 0] = fmaf(p, vv.x, acc[d + 0]);
                    acc[d + 1] = fmaf(p, vv.y, acc[d + 1]);
                    acc[d + 2] = fmaf(p, vv.z, acc[d + 2]);
                    acc[d + 3] = fmaf(p, vv.w, acc[d + 3]);
                }
            }
        }
    }
    if (qvalid) {
        float inv = 1.f / l;
        float* op = out + qrow * DM + hh * HDIM;
        #pragma unroll
        for (int d = 0; d < HDIM; d += 4) {
            float4 o;
            o.x = acc[d + 0] * inv; o.y = acc[d + 1] * inv;
            o.z = acc[d + 2] * inv; o.w = acc[d + 3] * inv;
            *(float4*)(op + d) = o;
        }
    }
}

// ---------------- head ----------------

__global__ __launch_bounds__(256) void head_kernel(const float* __restrict__ h,
                                                   const float* __restrict__ w1,
                                                   const float* __restrict__ b1,
                                                   const float* __restrict__ w2,
                                                   const float* __restrict__ b2,
                                                   float* __restrict__ out, int N) {
    const int b = blockIdx.x;
    const int t = threadIdx.x;
    __shared__ float cls[DM];
    __shared__ float hid[DM];
    cls[t] = h[(size_t)(N + b) * DM + t];
    __syncthreads();
    float s = b1[t];
    for (int k = 0; k < DM; ++k) s = fmaf(cls[k], w1[t * DM + k], s);
    hid[t] = fmaxf(s, 0.f);
    __syncthreads();
    if (t < 2) {
        float o = b2[t];
        for (int k = 0; k < DM; ++k) o = fmaf(hid[k], w2[t * DM + k], o);
        out[b * 2 + t] = o;
    }
}

// ---------------- launch ----------------

extern "C" void kernel_launch(void* const* d_in, const int* in_sizes, int n_in,
                              void* d_out, int out_size, void* d_ws, size_t ws_size,
                              hipStream_t stream) {
    const float* dom_emb   = (const float*)d_in[0];
    const int*   dom_idx   = (const int*)d_in[1];
    const float* geometry  = (const float*)d_in[3];
    const float* in_w      = (const float*)d_in[4];
    const float* in_b      = (const float*)d_in[5];
    const float* geo_w     = (const float*)d_in[6];
    const float* geo_b     = (const float*)d_in[7];
    const float* cls_tok   = (const float*)d_in[8];
    const float* qkv_w     = (const float*)d_in[9];
    const float* qkv_b     = (const float*)d_in[10];
    const float* out_w     = (const float*)d_in[11];
    const float* out_b     = (const float*)d_in[12];
    const float* ln1_w     = (const float*)d_in[13];
    const float* ln1_b     = (const float*)d_in[14];
    const float* ln2_w     = (const float*)d_in[15];
    const float* ln2_b     = (const float*)d_in[16];
    const float* ff_w1     = (const float*)d_in[17];
    const float* ff_b1     = (const float*)d_in[18];
    const float* ff_w2     = (const float*)d_in[19];
    const float* ff_b2     = (const float*)d_in[20];
    const float* head_w1   = (const float*)d_in[21];
    const float* head_b1   = (const float*)d_in[22];
    const float* head_w2   = (const float*)d_in[23];
    const float* head_b2   = (const float*)d_in[24];
    float* outp = (float*)d_out;

    const int N = in_sizes[0] / D_INPUT;       // 65536
    const int T = N + BEV;                     // 65664 = 513 * 128

    // workspace layout (bytes, all offsets 256-aligned)
    char* base = (char*)d_ws;
    size_t off = 0;
    int* counts = (int*)(base + off);              off += 1024;
    int* starts = (int*)(base + off);              off += 1024;
    float* We   = (float*)(base + off);            off += (size_t)256 * 384 * 4;  // 384 KB
    float* be   = (float*)(base + off);            off += 1024;
    float* h    = (float*)(base + off);            off += (size_t)T * DM * 4;     // 67.2 MB
    float* tmp  = (float*)(base + off);            off += (size_t)T * DM * 4;     // 67.2 MB
    char*  bigc = base + off;                      off += (size_t)T * 768 * 2;    // 100.9 MB
    // bigc is reused in three phases: fp32 A-matrix (N x 384), bf16 qkv (T x 768),
    // fp32 FF chunk (21888 x 1024 = 89.7 MB).
    float*          bigA  = (float*)bigc;
    unsigned short* qkvb  = (unsigned short*)bigc;
    float*          bigF  = (float*)bigc;

    if (ws_size < off) {   // insufficient workspace -> encode ws_size (MB) in output
        beacon_kernel<<<1, 256, 0, stream>>>(outp, out_size, (float)(ws_size >> 20));
        return;
    }

    // ---- event bookkeeping ----
    zero_counts_kernel<<<1, BEV, 0, stream>>>(counts);
    count_kernel<<<(N + 255) / 256, 256, 0, stream>>>(dom_idx, counts, N);
    scan_kernel<<<1, 64, 0, stream>>>(counts, starts);

    // ---- embed: h[0..N-1] = [emb | posenc] @ We^T + be ----
    prep_w_kernel<<<(256 * 384 + 255) / 256, 256, 0, stream>>>(in_w, geo_w, in_b, geo_b, We, be);
    prep_a_kernel<<<(int)(((size_t)N * 384 + 255) / 256), 256, 0, stream>>>(dom_emb, geometry, bigA, N);
    gemm_kernel<float><<<dim3(2, N / 128), 256, 0, stream>>>(bigA, We, be, h, 384, DM, 0);
    cls_kernel<<<BEV, DM, 0, stream>>>(cls_tok, h, N);

    // ---- transformer layers ----
    const int lnGrid = (T + 3) / 4;
    const int CH = 171 * 128;                   // 21888 rows per FF chunk, 3 chunks
    for (int l = 0; l < NLAYERS; ++l) {
        ln_kernel<<<lnGrid, 256, 0, stream>>>(h, ln1_w + l * DM, ln1_b + l * DM, tmp, T);
        gemm_kernel<unsigned short><<<dim3(6, T / 128), 256, 0, stream>>>(
            tmp, qkv_w + (size_t)l * 768 * DM, qkv_b + l * 768, qkvb, DM, 768, 0);
        attn_kernel<<<dim3(BEV * NHEADS, 3), 256, 0, stream>>>(qkvb, counts, starts, tmp, N);
        gemm_kernel<float><<<dim3(2, T / 128), 256, 0, stream>>>(
            tmp, out_w + (size_t)l * DM * DM, out_b + l * DM, h, DM, DM, 2);
        ln_kernel<<<lnGrid, 256, 0, stream>>>(h, ln2_w + l * DM, ln2_b + l * DM, tmp, T);
        for (int c = 0; c < 3; ++c) {
            const size_t r0 = (size_t)c * CH;
            gemm_kernel<float><<<dim3(8, 171), 256, 0, stream>>>(
                tmp + r0 * DM, ff_w1 + (size_t)l * DFF * DM, ff_b1 + l * DFF, bigF, DM, DFF, 1);
            gemm_kernel<float><<<dim3(2, 171), 256, 0, stream>>>(
                bigF, ff_w2 + (size_t)l * DM * DFF, ff_b2 + l * DM, h + r0 * DM, DFF, DM, 2);
        }
    }

    // ---- head ----
    head_kernel<<<BEV, DM, 0, stream>>>(h, head_w1, head_b1, head_w2, head_b2, outp, N);
}

// Round 3
// 4847.950 us; speedup vs baseline: 1.9745x; 1.9745x over previous
//
#include <hip/hip_runtime.h>
#include <hip/hip_bf16.h>
#include <math.h>

// EventTransformer on MI355X — round 2: bf16 MFMA GEMMs (m97 structure),
// scalar flash attention unchanged (bf16 qkv). Packed-token layout:
// rows 0..N-1 = DOM tokens (input order), rows N..N+B-1 = CLS tokens.

#define D_INPUT  128
#define DM       256
#define NHEADS   4
#define HDIM     64
#define NLAYERS  4
#define DFF      1024
#define BEV      128
#define LNEPS    1e-5f

typedef unsigned short u16;
typedef __attribute__((ext_vector_type(8))) short bf16x8;
typedef __attribute__((ext_vector_type(4))) float f32x4;

__device__ inline float bf2f(u16 u) {
    union { unsigned int i; float f; } c; c.i = ((unsigned int)u) << 16; return c.f;
}
__device__ inline u16 f2bf(float x) {
    unsigned int xi = __float_as_uint(x);
    unsigned int r  = xi + 0x7FFFu + ((xi >> 16) & 1u);   // RNE
    return (u16)(r >> 16);
}

// async global->LDS, 16B per lane; LDS dest must be wave-uniform base + lane*16
__device__ inline void gload16(const void* g, void* l) {
    __builtin_amdgcn_global_load_lds(
        (const __attribute__((address_space(1))) unsigned int*)g,
        (__attribute__((address_space(3))) unsigned int*)l, 16, 0, 0);
}

// ---------------- prep kernels ----------------

__global__ void zero_counts_kernel(int* counts) { counts[threadIdx.x] = 0; }

__global__ void count_kernel(const int* __restrict__ idx, int* __restrict__ counts, int N) {
    int i = blockIdx.x * blockDim.x + threadIdx.x;
    if (i < N) atomicAdd(&counts[idx[i]], 1);
}

__global__ void scan_kernel(const int* __restrict__ counts, int* __restrict__ starts) {
    if (threadIdx.x == 0) {
        int s = 0;
        for (int b = 0; b < BEV; ++b) { starts[b] = s; s += counts[b]; }
    }
}

__global__ void beacon_kernel(float* out, int n, float v) {
    int i = blockIdx.x * blockDim.x + threadIdx.x;
    if (i < n) out[i] = v;
}

__global__ void cvt_kernel(const float* __restrict__ in, u16* __restrict__ out, int n) {
    int i = blockIdx.x * blockDim.x + threadIdx.x;
    if (i < n) out[i] = f2bf(in[i]);
}

// We (256 x 384) bf16 = [in_proj_w | geo_proj_w[:, :252] | 0]; be = in_b + geo_b (f32).
__global__ void prep_w_kernel(const float* __restrict__ win, const float* __restrict__ wgeo,
                              const float* __restrict__ bin, const float* __restrict__ bgeo,
                              u16* __restrict__ We, float* __restrict__ be) {
    int i = blockIdx.x * blockDim.x + threadIdx.x;
    if (i < 256 * 384) {
        int o = i / 384, k = i % 384;
        float v = 0.f;
        if (k < 128)      v = win[o * 128 + k];
        else if (k < 380) v = wgeo[o * 256 + (k - 128)];
        We[i] = f2bf(v);
    }
    if (i < 256) be[i] = bin[i] + bgeo[i];
}

// A (N x 384) bf16 = [dom_embeddings | pos_enc (252) | 0].
__global__ void prep_a_kernel(const float* __restrict__ emb, const float* __restrict__ geo,
                              u16* __restrict__ A, int N) {
    size_t i = (size_t)blockIdx.x * blockDim.x + threadIdx.x;
    if (i >= (size_t)N * 384) return;
    int k = (int)(i % 384);
    size_t r = i / 384;
    float v = 0.f;
    if (k < 128) {
        v = emb[r * 128 + k];
    } else if (k < 380) {
        int rem  = k - 128;
        int axis = rem / 84;
        int r2   = rem % 84;
        int band = r2 >> 1;
        int sc   = r2 & 1;
        float freq = expf((float)band * (2.3025850929940457f / 41.0f)); // 10^(band/41)
        float ang  = (6.283185307179586f * geo[r * 3 + axis]) * freq;
        v = sc ? cosf(ang) : sinf(ang);
    }
    A[i] = f2bf(v);
}

__global__ void cls_kernel(const float* __restrict__ cls, float* __restrict__ h, int N) {
    h[(size_t)(N + blockIdx.x) * DM + threadIdx.x] = cls[threadIdx.x];
}

// ---------------- layernorm: fp32 in, bf16 out; one wave per row ----------------

__global__ __launch_bounds__(256) void ln_kernel(const float* __restrict__ x,
                                                 const float* __restrict__ w,
                                                 const float* __restrict__ b,
                                                 u16* __restrict__ y, int T) {
    int row  = blockIdx.x * 4 + (threadIdx.x >> 6);
    int lane = threadIdx.x & 63;
    if (row >= T) return;
    float4 v = ((const float4*)(x + (size_t)row * DM))[lane];
    float s = v.x + v.y + v.z + v.w;
    #pragma unroll
    for (int off = 32; off > 0; off >>= 1) s += __shfl_xor(s, off);
    float mean = s * (1.0f / 256.0f);
    float dx = v.x - mean, dy = v.y - mean, dz = v.z - mean, dw = v.w - mean;
    float ss = dx * dx + dy * dy + dz * dz + dw * dw;
    #pragma unroll
    for (int off = 32; off > 0; off >>= 1) ss += __shfl_xor(ss, off);
    float inv = rsqrtf(ss * (1.0f / 256.0f) + LNEPS);
    float4 wv = ((const float4*)w)[lane];
    float4 bv = ((const float4*)b)[lane];
    ushort4 o;
    o.x = f2bf(dx * inv * wv.x + bv.x);
    o.y = f2bf(dy * inv * wv.y + bv.y);
    o.z = f2bf(dz * inv * wv.z + bv.z);
    o.w = f2bf(dw * inv * wv.w + bv.w);
    ((ushort4*)(y + (size_t)row * DM))[lane] = o;
}

// ---------------- bf16 MFMA GEMM: C[M,No] = A[M,K] @ W[No,K]^T + bias ----------------
// m97 structure: 128x128 tile, BK=64, 4 waves each computing a 64x64 quadrant via
// 4x4 grid of 16x16x32 MFMAs. A,W bf16 row-major; K%64==0, M%128==0, No%128==0.
// OutT: float (flags: 1 relu, 2 residual-add) or u16 (bf16 store, relu ok).

template <typename OutT>
__global__ __launch_bounds__(256) void mgemm_kernel(const u16* __restrict__ A,
                                                    const u16* __restrict__ W,
                                                    const float* __restrict__ bias,
                                                    OutT* __restrict__ C,
                                                    int K, int No, int flags) {
    __shared__ u16 As[128 * 64];
    __shared__ u16 Bs[128 * 64];
    const int m0 = blockIdx.y * 128, n0 = blockIdx.x * 128;
    const int tid  = threadIdx.x;
    const int w    = tid >> 6, lane = tid & 63;
    const int wr   = w >> 1,  wc   = w & 1;
    const int lhi  = lane >> 4, llo = lane & 15;

    f32x4 acc[4][4];
    #pragma unroll
    for (int i = 0; i < 4; ++i)
        #pragma unroll
        for (int j = 0; j < 4; ++j) acc[i][j] = (f32x4){0.f, 0.f, 0.f, 0.f};

    for (int kt = 0; kt < K; kt += 64) {
        __syncthreads();              // previous iteration's LDS reads complete
        #pragma unroll
        for (int it = 0; it < 4; ++it) {
            int un = it * 256 + tid;  // 16B unit; row = un/8, 16B-chunk = un%8
            int r = un >> 3, c8 = un & 7;
            gload16(A + (size_t)(m0 + r) * K + kt + c8 * 8, &As[un * 8]);
            gload16(W + (size_t)(n0 + r) * K + kt + c8 * 8, &Bs[un * 8]);
        }
        __syncthreads();              // compiler drains vmcnt before barrier
        #pragma unroll
        for (int kk = 0; kk < 2; ++kk) {
            bf16x8 af[4], bfr[4];
            #pragma unroll
            for (int i = 0; i < 4; ++i)
                af[i] = *(const bf16x8*)&As[(wr * 64 + i * 16 + llo) * 64 + kk * 32 + lhi * 8];
            #pragma unroll
            for (int j = 0; j < 4; ++j)
                bfr[j] = *(const bf16x8*)&Bs[(wc * 64 + j * 16 + llo) * 64 + kk * 32 + lhi * 8];
            #pragma unroll
            for (int i = 0; i < 4; ++i)
                #pragma unroll
                for (int j = 0; j < 4; ++j)
                    acc[i][j] = __builtin_amdgcn_mfma_f32_16x16x32_bf16(af[i], bfr[j], acc[i][j], 0, 0, 0);
        }
    }

    // epilogue: C/D layout (m89-verified): col = lane&15, row = (lane>>4)*4 + reg
    #pragma unroll
    for (int i = 0; i < 4; ++i) {
        #pragma unroll
        for (int j = 0; j < 4; ++j) {
            const int row0 = m0 + wr * 64 + i * 16 + lhi * 4;
            const int col  = n0 + wc * 64 + j * 16 + llo;
            const float bb = bias[col];
            #pragma unroll
            for (int r = 0; r < 4; ++r) {
                float v = acc[i][j][r] + bb;
                size_t idx = (size_t)(row0 + r) * No + col;
                if constexpr (sizeof(OutT) == 4) {
                    float* cp = (float*)C + idx;
                    if (flags & 2) v += *cp;
                    if (flags & 1) v = fmaxf(v, 0.f);
                    *cp = v;
                } else {
                    if (flags & 1) v = fmaxf(v, 0.f);
                    ((u16*)C)[idx] = f2bf(v);
                }
            }
        }
    }
}

// ---------------- attention: thread-per-query flash over bf16 qkv ----------------

#define CK 64

__global__ __launch_bounds__(256) void attn_kernel(const u16* __restrict__ qkv,
                                                   const int* __restrict__ counts,
                                                   const int* __restrict__ starts,
                                                   u16* __restrict__ out, int N) {
    const int b  = blockIdx.x >> 2;
    const int hh = blockIdx.x & 3;
    const int Sb = counts[b] + 1;
    const int qbase = blockIdx.y * 256;
    if (qbase >= Sb) return;
    __shared__ float Ks[CK][HDIM];
    __shared__ float Vs[CK][HDIM];
    const int t = threadIdx.x;
    const int start = starts[b];
    const int qi = qbase + t;
    const bool qvalid = qi < Sb;
    const size_t qrow = qvalid ? (qi == 0 ? (size_t)(N + b) : (size_t)(start + qi - 1))
                               : (size_t)(N + b);
    const u16* qp = qkv + qrow * 768 + hh * HDIM;

    float q[HDIM];
    #pragma unroll
    for (int d = 0; d < HDIM; d += 4) {
        ushort4 u = *(const ushort4*)(qp + d);
        q[d + 0] = bf2f(u.x) * 0.125f;  q[d + 1] = bf2f(u.y) * 0.125f;
        q[d + 2] = bf2f(u.z) * 0.125f;  q[d + 3] = bf2f(u.w) * 0.125f;
    }
    float acc[HDIM];
    #pragma unroll
    for (int d = 0; d < HDIM; ++d) acc[d] = 0.f;
    float m = -1e30f, l = 0.f;

    const int kk = t >> 2;
    const int kp = t & 3;

    for (int kbase = 0; kbase < Sb; kbase += CK) {
        int nk = Sb - kbase; if (nk > CK) nk = CK;
        __syncthreads();
        if (kk < nk) {
            int ki = kbase + kk;
            size_t krow = (ki == 0) ? (size_t)(N + b) : (size_t)(start + ki - 1);
            const u16* kpp = qkv + krow * 768 + 256 + hh * HDIM + kp * 16;
            const u16* vpp = qkv + krow * 768 + 512 + hh * HDIM + kp * 16;
            #pragma unroll
            for (int u2 = 0; u2 < 4; ++u2) {
                ushort4 uk = *(const ushort4*)(kpp + u2 * 4);
                ushort4 uv = *(const ushort4*)(vpp + u2 * 4);
                float4 fk = {bf2f(uk.x), bf2f(uk.y), bf2f(uk.z), bf2f(uk.w)};
                float4 fv = {bf2f(uv.x), bf2f(uv.y), bf2f(uv.z), bf2f(uv.w)};
                *(float4*)&Ks[kk][kp * 16 + u2 * 4] = fk;
                *(float4*)&Vs[kk][kp * 16 + u2 * 4] = fv;
            }
        }
        __syncthreads();
        if (qvalid) {
            for (int k = 0; k < nk; ++k) {
                float s = 0.f;
                #pragma unroll
                for (int d = 0; d < HDIM; d += 4) {
                    float4 kv = *(const float4*)&Ks[k][d];
                    s = fmaf(q[d + 0], kv.x, s); s = fmaf(q[d + 1], kv.y, s);
                    s = fmaf(q[d + 2], kv.z, s); s = fmaf(q[d + 3], kv.w, s);
                }
                if (s > m) {
                    float sc = __expf(m - s);
                    l *= sc;
                    #pragma unroll
                    for (int d = 0; d < HDIM; ++d) acc[d] *= sc;
                    m = s;
                }
                float p = __expf(s - m);
                l += p;
                #pragma unroll
                for (int d = 0; d < HDIM; d += 4) {
                    float4 vv = *(const float4*)&Vs[k][d];
                    acc[d + 0] = fmaf(p, vv.x, acc[d + 0]);
                    acc[d + 1] = fmaf(p, vv.y, acc[d + 1]);
                    acc[d + 2] = fmaf(p, vv.z, acc[d + 2]);
                    acc[d + 3] = fmaf(p, vv.w, acc[d + 3]);
                }
            }
        }
    }
    if (qvalid) {
        float inv = 1.f / l;
        u16* op = out + qrow * DM + hh * HDIM;
        #pragma unroll
        for (int d = 0; d < HDIM; d += 4) {
            ushort4 o;
            o.x = f2bf(acc[d + 0] * inv); o.y = f2bf(acc[d + 1] * inv);
            o.z = f2bf(acc[d + 2] * inv); o.w = f2bf(acc[d + 3] * inv);
            *(ushort4*)(op + d) = o;
        }
    }
}

// ---------------- head ----------------

__global__ __launch_bounds__(256) void head_kernel(const float* __restrict__ h,
                                                   const float* __restrict__ w1,
                                                   const float* __restrict__ b1,
                                                   const float* __restrict__ w2,
                                                   const float* __restrict__ b2,
                                                   float* __restrict__ out, int N) {
    const int b = blockIdx.x;
    const int t = threadIdx.x;
    __shared__ float cls[DM];
    __shared__ float hid[DM];
    cls[t] = h[(size_t)(N + b) * DM + t];
    __syncthreads();
    float s = b1[t];
    for (int k = 0; k < DM; ++k) s = fmaf(cls[k], w1[t * DM + k], s);
    hid[t] = fmaxf(s, 0.f);
    __syncthreads();
    if (t < 2) {
        float o = b2[t];
        for (int k = 0; k < DM; ++k) o = fmaf(hid[k], w2[t * DM + k], o);
        out[b * 2 + t] = o;
    }
}

// ---------------- launch ----------------

extern "C" void kernel_launch(void* const* d_in, const int* in_sizes, int n_in,
                              void* d_out, int out_size, void* d_ws, size_t ws_size,
                              hipStream_t stream) {
    const float* dom_emb   = (const float*)d_in[0];
    const int*   dom_idx   = (const int*)d_in[1];
    const float* geometry  = (const float*)d_in[3];
    const float* in_w      = (const float*)d_in[4];
    const float* in_b      = (const float*)d_in[5];
    const float* geo_w     = (const float*)d_in[6];
    const float* geo_b     = (const float*)d_in[7];
    const float* cls_tok   = (const float*)d_in[8];
    const float* qkv_w     = (const float*)d_in[9];
    const float* qkv_b     = (const float*)d_in[10];
    const float* out_w     = (const float*)d_in[11];
    const float* out_b     = (const float*)d_in[12];
    const float* ln1_w     = (const float*)d_in[13];
    const float* ln1_b     = (const float*)d_in[14];
    const float* ln2_w     = (const float*)d_in[15];
    const float* ln2_b     = (const float*)d_in[16];
    const float* ff_w1     = (const float*)d_in[17];
    const float* ff_b1     = (const float*)d_in[18];
    const float* ff_w2     = (const float*)d_in[19];
    const float* ff_b2     = (const float*)d_in[20];
    const float* head_w1   = (const float*)d_in[21];
    const float* head_b1   = (const float*)d_in[22];
    const float* head_w2   = (const float*)d_in[23];
    const float* head_b2   = (const float*)d_in[24];
    float* outp = (float*)d_out;

    const int N = in_sizes[0] / D_INPUT;       // 65536
    const int T = N + BEV;                     // 65664 = 513 * 128

    // workspace layout (bytes, all sizes 256-aligned). Total ~208.3 MB.
    char* base = (char*)d_ws;
    size_t off = 0;
    int* counts = (int*)(base + off);          off += 1024;
    int* starts = (int*)(base + off);          off += 1024;
    u16*   Web  = (u16*)(base + off);          off += (size_t)256 * 384 * 2;
    float* be   = (float*)(base + off);        off += 1024;
    u16*   wq   = (u16*)(base + off);          off += (size_t)NLAYERS * 768 * 256 * 2;
    u16*   wo   = (u16*)(base + off);          off += (size_t)NLAYERS * 256 * 256 * 2;
    u16*   w1b  = (u16*)(base + off);          off += (size_t)NLAYERS * 1024 * 256 * 2;
    u16*   w2b  = (u16*)(base + off);          off += (size_t)NLAYERS * 256 * 1024 * 2;
    float* h    = (float*)(base + off);        off += (size_t)T * DM * 4;     // 67.2 MB
    u16*   xb   = (u16*)(base + off);          off += (size_t)T * DM * 2;     // 33.6 MB
    char*  bigc = base + off;                  off += (size_t)T * 768 * 2;    // 100.9 MB
    // bigc phases: bf16 embed A (N x 384 = 50.3MB) -> bf16 qkv (T x 768) ->
    // bf16 FF chunk (21888 x 1024 = 44.8MB, 3 chunks)
    u16* Ab   = (u16*)bigc;
    u16* qkvb = (u16*)bigc;
    u16* ffm  = (u16*)bigc;

    if (ws_size < off) {   // insufficient workspace -> encode ws_size (MB) in output
        beacon_kernel<<<1, 256, 0, stream>>>(outp, out_size, (float)(ws_size >> 20));
        return;
    }

    // ---- weight conversion to bf16 ----
    cvt_kernel<<<(NLAYERS * 768 * 256 + 255) / 256, 256, 0, stream>>>(qkv_w, wq, NLAYERS * 768 * 256);
    cvt_kernel<<<(NLAYERS * 256 * 256 + 255) / 256, 256, 0, stream>>>(out_w, wo, NLAYERS * 256 * 256);
    cvt_kernel<<<(NLAYERS * 1024 * 256 + 255) / 256, 256, 0, stream>>>(ff_w1, w1b, NLAYERS * 1024 * 256);
    cvt_kernel<<<(NLAYERS * 256 * 1024 + 255) / 256, 256, 0, stream>>>(ff_w2, w2b, NLAYERS * 256 * 1024);
    prep_w_kernel<<<(256 * 384 + 255) / 256, 256, 0, stream>>>(in_w, geo_w, in_b, geo_b, Web, be);

    // ---- event bookkeeping ----
    zero_counts_kernel<<<1, BEV, 0, stream>>>(counts);
    count_kernel<<<(N + 255) / 256, 256, 0, stream>>>(dom_idx, counts, N);
    scan_kernel<<<1, 64, 0, stream>>>(counts, starts);

    // ---- embed ----
    prep_a_kernel<<<(int)(((size_t)N * 384 + 255) / 256), 256, 0, stream>>>(dom_emb, geometry, Ab, N);
    mgemm_kernel<float><<<dim3(2, N / 128), 256, 0, stream>>>(Ab, Web, be, h, 384, DM, 0);
    cls_kernel<<<BEV, DM, 0, stream>>>(cls_tok, h, N);

    // ---- transformer layers ----
    const int lnGrid = (T + 3) / 4;
    const int CH = 171 * 128;                   // 21888 rows per FF chunk, 3 chunks
    for (int l = 0; l < NLAYERS; ++l) {
        ln_kernel<<<lnGrid, 256, 0, stream>>>(h, ln1_w + l * DM, ln1_b + l * DM, xb, T);
        mgemm_kernel<u16><<<dim3(6, T / 128), 256, 0, stream>>>(
            xb, wq + (size_t)l * 768 * 256, qkv_b + l * 768, qkvb, 256, 768, 0);
        attn_kernel<<<dim3(BEV * NHEADS, 3), 256, 0, stream>>>(qkvb, counts, starts, xb, N);
        mgemm_kernel<float><<<dim3(2, T / 128), 256, 0, stream>>>(
            xb, wo + (size_t)l * 256 * 256, out_b + l * DM, h, 256, DM, 2);
        ln_kernel<<<lnGrid, 256, 0, stream>>>(h, ln2_w + l * DM, ln2_b + l * DM, xb, T);
        for (int c = 0; c < 3; ++c) {
            const size_t r0 = (size_t)c * CH;
            mgemm_kernel<u16><<<dim3(8, 171), 256, 0, stream>>>(
                xb + r0 * DM, w1b + (size_t)l * DFF * 256, ff_b1 + l * DFF, ffm, 256, DFF, 1);
            mgemm_kernel<float><<<dim3(2, 171), 256, 0, stream>>>(
                ffm, w2b + (size_t)l * 256 * DFF, ff_b2 + l * DM, h + r0 * DM, DFF, DM, 2);
        }
    }

    // ---- head ----
    head_kernel<<<BEV, DM, 0, stream>>>(h, head_w1, head_b1, head_w2, head_b2, outp, N);
}

// Round 4
// 2475.181 us; speedup vs baseline: 3.8674x; 1.9586x over previous
//
#include <hip/hip_runtime.h>
#include <hip/hip_bf16.h>
#include <math.h>

// EventTransformer on MI355X — round 3: MFMA flash attention + bf16 MFMA GEMMs.
// Packed-token layout: rows 0..N-1 = DOM tokens, rows N..N+B-1 = CLS tokens.

#define D_INPUT  128
#define DM       256
#define NHEADS   4
#define HDIM     64
#define NLAYERS  4
#define DFF      1024
#define BEV      128
#define LNEPS    1e-5f
#define KVB      64
#define LSTR     72   // LDS row stride (u16): 144 B = 9*16 keeps 16B alignment, breaks 32-way conflicts

typedef unsigned short u16;
typedef __attribute__((ext_vector_type(8))) short bf16x8;
typedef __attribute__((ext_vector_type(4))) float f32x4;

__device__ inline float bf2f(u16 u) {
    union { unsigned int i; float f; } c; c.i = ((unsigned int)u) << 16; return c.f;
}
__device__ inline u16 f2bf(float x) {
    unsigned int xi = __float_as_uint(x);
    unsigned int r  = xi + 0x7FFFu + ((xi >> 16) & 1u);   // RNE
    return (u16)(r >> 16);
}

// async global->LDS, 16B per lane; LDS dest must be wave-uniform base + lane*16
__device__ inline void gload16(const void* g, void* l) {
    __builtin_amdgcn_global_load_lds(
        (const __attribute__((address_space(1))) unsigned int*)g,
        (__attribute__((address_space(3))) unsigned int*)l, 16, 0, 0);
}

// ---------------- prep kernels ----------------

__global__ void zero_counts_kernel(int* counts) { counts[threadIdx.x] = 0; }

__global__ void count_kernel(const int* __restrict__ idx, int* __restrict__ counts, int N) {
    int i = blockIdx.x * blockDim.x + threadIdx.x;
    if (i < N) atomicAdd(&counts[idx[i]], 1);
}

__global__ void scan_kernel(const int* __restrict__ counts, int* __restrict__ starts) {
    if (threadIdx.x == 0) {
        int s = 0;
        for (int b = 0; b < BEV; ++b) { starts[b] = s; s += counts[b]; }
    }
}

__global__ void beacon_kernel(float* out, int n, float v) {
    int i = blockIdx.x * blockDim.x + threadIdx.x;
    if (i < n) out[i] = v;
}

__global__ void cvt_kernel(const float* __restrict__ in, u16* __restrict__ out, int n) {
    int i = blockIdx.x * blockDim.x + threadIdx.x;
    if (i < n) out[i] = f2bf(in[i]);
}

// We (256 x 384) bf16 = [in_proj_w | geo_proj_w[:, :252] | 0]; be = in_b + geo_b (f32).
__global__ void prep_w_kernel(const float* __restrict__ win, const float* __restrict__ wgeo,
                              const float* __restrict__ bin, const float* __restrict__ bgeo,
                              u16* __restrict__ We, float* __restrict__ be) {
    int i = blockIdx.x * blockDim.x + threadIdx.x;
    if (i < 256 * 384) {
        int o = i / 384, k = i % 384;
        float v = 0.f;
        if (k < 128)      v = win[o * 128 + k];
        else if (k < 380) v = wgeo[o * 256 + (k - 128)];
        We[i] = f2bf(v);
    }
    if (i < 256) be[i] = bin[i] + bgeo[i];
}

// A (N x 384) bf16 = [dom_embeddings | pos_enc (252) | 0].
__global__ void prep_a_kernel(const float* __restrict__ emb, const float* __restrict__ geo,
                              u16* __restrict__ A, int N) {
    size_t i = (size_t)blockIdx.x * blockDim.x + threadIdx.x;
    if (i >= (size_t)N * 384) return;
    int k = (int)(i % 384);
    size_t r = i / 384;
    float v = 0.f;
    if (k < 128) {
        v = emb[r * 128 + k];
    } else if (k < 380) {
        int rem  = k - 128;
        int axis = rem / 84;
        int r2   = rem % 84;
        int band = r2 >> 1;
        int sc   = r2 & 1;
        float freq = expf((float)band * (2.3025850929940457f / 41.0f)); // 10^(band/41)
        float ang  = (6.283185307179586f * geo[r * 3 + axis]) * freq;
        v = sc ? cosf(ang) : sinf(ang);
    }
    A[i] = f2bf(v);
}

__global__ void cls_kernel(const float* __restrict__ cls, float* __restrict__ h, int N) {
    h[(size_t)(N + blockIdx.x) * DM + threadIdx.x] = cls[threadIdx.x];
}

// ---------------- layernorm: fp32 in, bf16 out; one wave per row ----------------

__global__ __launch_bounds__(256) void ln_kernel(const float* __restrict__ x,
                                                 const float* __restrict__ w,
                                                 const float* __restrict__ b,
                                                 u16* __restrict__ y, int T) {
    int row  = blockIdx.x * 4 + (threadIdx.x >> 6);
    int lane = threadIdx.x & 63;
    if (row >= T) return;
    float4 v = ((const float4*)(x + (size_t)row * DM))[lane];
    float s = v.x + v.y + v.z + v.w;
    #pragma unroll
    for (int off = 32; off > 0; off >>= 1) s += __shfl_xor(s, off);
    float mean = s * (1.0f / 256.0f);
    float dx = v.x - mean, dy = v.y - mean, dz = v.z - mean, dw = v.w - mean;
    float ss = dx * dx + dy * dy + dz * dz + dw * dw;
    #pragma unroll
    for (int off = 32; off > 0; off >>= 1) ss += __shfl_xor(ss, off);
    float inv = rsqrtf(ss * (1.0f / 256.0f) + LNEPS);
    float4 wv = ((const float4*)w)[lane];
    float4 bv = ((const float4*)b)[lane];
    ushort4 o;
    o.x = f2bf(dx * inv * wv.x + bv.x);
    o.y = f2bf(dy * inv * wv.y + bv.y);
    o.z = f2bf(dz * inv * wv.z + bv.z);
    o.w = f2bf(dw * inv * wv.w + bv.w);
    ((ushort4*)(y + (size_t)row * DM))[lane] = o;
}

// ---------------- bf16 MFMA GEMM (m97 structure, validated round 2) ----------------

template <typename OutT>
__global__ __launch_bounds__(256) void mgemm_kernel(const u16* __restrict__ A,
                                                    const u16* __restrict__ W,
                                                    const float* __restrict__ bias,
                                                    OutT* __restrict__ C,
                                                    int K, int No, int flags) {
    __shared__ u16 As[128 * 64];
    __shared__ u16 Bs[128 * 64];
    const int m0 = blockIdx.y * 128, n0 = blockIdx.x * 128;
    const int tid  = threadIdx.x;
    const int w    = tid >> 6, lane = tid & 63;
    const int wr   = w >> 1,  wc   = w & 1;
    const int lhi  = lane >> 4, llo = lane & 15;

    f32x4 acc[4][4];
    #pragma unroll
    for (int i = 0; i < 4; ++i)
        #pragma unroll
        for (int j = 0; j < 4; ++j) acc[i][j] = (f32x4){0.f, 0.f, 0.f, 0.f};

    for (int kt = 0; kt < K; kt += 64) {
        __syncthreads();
        #pragma unroll
        for (int it = 0; it < 4; ++it) {
            int un = it * 256 + tid;
            int r = un >> 3, c8 = un & 7;
            gload16(A + (size_t)(m0 + r) * K + kt + c8 * 8, &As[un * 8]);
            gload16(W + (size_t)(n0 + r) * K + kt + c8 * 8, &Bs[un * 8]);
        }
        __syncthreads();
        #pragma unroll
        for (int kk = 0; kk < 2; ++kk) {
            bf16x8 af[4], bfr[4];
            #pragma unroll
            for (int i = 0; i < 4; ++i)
                af[i] = *(const bf16x8*)&As[(wr * 64 + i * 16 + llo) * 64 + kk * 32 + lhi * 8];
            #pragma unroll
            for (int j = 0; j < 4; ++j)
                bfr[j] = *(const bf16x8*)&Bs[(wc * 64 + j * 16 + llo) * 64 + kk * 32 + lhi * 8];
            #pragma unroll
            for (int i = 0; i < 4; ++i)
                #pragma unroll
                for (int j = 0; j < 4; ++j)
                    acc[i][j] = __builtin_amdgcn_mfma_f32_16x16x32_bf16(af[i], bfr[j], acc[i][j], 0, 0, 0);
        }
    }

    #pragma unroll
    for (int i = 0; i < 4; ++i) {
        #pragma unroll
        for (int j = 0; j < 4; ++j) {
            const int row0 = m0 + wr * 64 + i * 16 + lhi * 4;
            const int col  = n0 + wc * 64 + j * 16 + llo;
            const float bb = bias[col];
            #pragma unroll
            for (int r = 0; r < 4; ++r) {
                float v = acc[i][j][r] + bb;
                size_t idx = (size_t)(row0 + r) * No + col;
                if constexpr (sizeof(OutT) == 4) {
                    float* cp = (float*)C + idx;
                    if (flags & 2) v += *cp;
                    if (flags & 1) v = fmaxf(v, 0.f);
                    *cp = v;
                } else {
                    if (flags & 1) v = fmaxf(v, 0.f);
                    ((u16*)C)[idx] = f2bf(v);
                }
            }
        }
    }
}

// ---------------- MFMA flash attention ----------------
// Block = (event b, head h); 4 waves x 16 q-rows = 64-query tile, KV tiles of 64.
// qkv (T,768) bf16 [q|k|v]. Row for (b,s): s==0 -> N+b else starts[b]+s-1.
// Fragment conventions identical to mgemm (validated): A-frag row=lane&15,
// k=(lane>>4)*8; C/D col=lane&15, row=(lane>>4)*4+reg.

__global__ __launch_bounds__(256) void mattn_kernel(const u16* __restrict__ qkv,
                                                    const int* __restrict__ counts,
                                                    const int* __restrict__ starts,
                                                    u16* __restrict__ out, int N) {
    const int b  = blockIdx.x >> 2;
    const int hh = blockIdx.x & 3;
    const int Sb = counts[b] + 1;
    const int start = starts[b];
    __shared__ u16 Ks[KVB * LSTR];    // [k][d]
    __shared__ u16 Vt[HDIM * LSTR];   // [d][k] (transposed)
    __shared__ u16 Pl[4][16 * LSTR];  // per-wave P round-trip
    const int tid = threadIdx.x;
    const int w   = tid >> 6, lane = tid & 63;
    const int llo = lane & 15, lhi = lane >> 4;
    const int sr  = tid >> 2, sseg = tid & 3;   // staging: row 0..63, 16-d segment 0..3

    for (int qbase = blockIdx.y * 64; qbase < Sb; qbase += 16 * 64) {
        // Q fragments: lane holds q-row (w*16+llo), d = kk*32 + lhi*8 .. +7
        const int qi = qbase + w * 16 + llo;
        const size_t grow = (qi < Sb && qi > 0) ? (size_t)(start + qi - 1) : (size_t)(N + b);
        bf16x8 aq[2];
        aq[0] = *(const bf16x8*)(qkv + grow * 768 + hh * HDIM + lhi * 8);
        aq[1] = *(const bf16x8*)(qkv + grow * 768 + hh * HDIM + 32 + lhi * 8);

        f32x4 acc[4];
        #pragma unroll
        for (int jd = 0; jd < 4; ++jd) acc[jd] = (f32x4){0.f, 0.f, 0.f, 0.f};
        float m[4] = {-1e30f, -1e30f, -1e30f, -1e30f};
        float l[4] = {0.f, 0.f, 0.f, 0.f};

        for (int kbase = 0; kbase < Sb; kbase += KVB) {
            const int nk = min(KVB, Sb - kbase);
            __syncthreads();   // previous tile's LDS reads complete
            if (sr < nk) {
                const int ki = kbase + sr;
                const size_t krow = (ki == 0) ? (size_t)(N + b) : (size_t)(start + ki - 1);
                const u16* kp = qkv + krow * 768 + 256 + hh * HDIM + sseg * 16;
                const u16* vp = qkv + krow * 768 + 512 + hh * HDIM + sseg * 16;
                *(uint4*)&Ks[sr * LSTR + sseg * 16]     = *(const uint4*)kp;
                *(uint4*)&Ks[sr * LSTR + sseg * 16 + 8] = *(const uint4*)(kp + 8);
                u16 vv[16];
                *(uint4*)&vv[0] = *(const uint4*)vp;
                *(uint4*)&vv[8] = *(const uint4*)(vp + 8);
                #pragma unroll
                for (int u = 0; u < 16; ++u) Vt[(sseg * 16 + u) * LSTR + sr] = vv[u];
            } else {
                const uint4 z = {0, 0, 0, 0};
                *(uint4*)&Ks[sr * LSTR + sseg * 16]     = z;
                *(uint4*)&Ks[sr * LSTR + sseg * 16 + 8] = z;
                #pragma unroll
                for (int u = 0; u < 16; ++u) Vt[(sseg * 16 + u) * LSTR + sr] = 0;
            }
            __syncthreads();

            // QK^T: 4 score tiles of 16q x 16k
            f32x4 sc[4];
            #pragma unroll
            for (int j = 0; j < 4; ++j) sc[j] = (f32x4){0.f, 0.f, 0.f, 0.f};
            #pragma unroll
            for (int kk = 0; kk < 2; ++kk) {
                #pragma unroll
                for (int j = 0; j < 4; ++j) {
                    bf16x8 bk = *(const bf16x8*)&Ks[(j * 16 + llo) * LSTR + kk * 32 + lhi * 8];
                    sc[j] = __builtin_amdgcn_mfma_f32_16x16x32_bf16(aq[kk], bk, sc[j], 0, 0, 0);
                }
            }

            // scale + mask; per-lane score (q-row = lhi*4+reg, k-col = j*16+llo)
            float sj[4][4];     // [j][reg]
            float rmax[4] = {-1e30f, -1e30f, -1e30f, -1e30f};
            #pragma unroll
            for (int j = 0; j < 4; ++j) {
                const bool kin = (kbase + j * 16 + llo) < Sb;
                #pragma unroll
                for (int r = 0; r < 4; ++r) {
                    float s = kin ? sc[j][r] * 0.125f : -1e30f;
                    sj[j][r] = s;
                    rmax[r] = fmaxf(rmax[r], s);
                }
            }
            #pragma unroll
            for (int r = 0; r < 4; ++r) {
                #pragma unroll
                for (int mk = 1; mk < 16; mk <<= 1)
                    rmax[r] = fmaxf(rmax[r], __shfl_xor(rmax[r], mk));
            }

            // online softmax update + P -> bf16 -> LDS
            #pragma unroll
            for (int r = 0; r < 4; ++r) {
                const float mnew = fmaxf(m[r], rmax[r]);
                const float corr = __expf(m[r] - mnew);
                float lsum = 0.f;
                #pragma unroll
                for (int j = 0; j < 4; ++j) {
                    const float p = __expf(sj[j][r] - mnew);
                    lsum += p;
                    Pl[w][(lhi * 4 + r) * LSTR + j * 16 + llo] = f2bf(p);
                }
                #pragma unroll
                for (int mk = 1; mk < 16; mk <<= 1) lsum += __shfl_xor(lsum, mk);
                l[r] = l[r] * corr + lsum;
                m[r] = mnew;
                #pragma unroll
                for (int jd = 0; jd < 4; ++jd) acc[jd][r] *= corr;
            }

            // PV: O[16q x 64d] += P[16q x 64k] @ V[64k x 64d]
            #pragma unroll
            for (int kk2 = 0; kk2 < 2; ++kk2) {
                bf16x8 ap = *(const bf16x8*)&Pl[w][llo * LSTR + kk2 * 32 + lhi * 8];
                #pragma unroll
                for (int jd = 0; jd < 4; ++jd) {
                    bf16x8 bv = *(const bf16x8*)&Vt[(jd * 16 + llo) * LSTR + kk2 * 32 + lhi * 8];
                    acc[jd] = __builtin_amdgcn_mfma_f32_16x16x32_bf16(ap, bv, acc[jd], 0, 0, 0);
                }
            }
        }

        // write O: row = qbase + w*16 + lhi*4 + reg, col = hh*64 + jd*16 + llo
        #pragma unroll
        for (int r = 0; r < 4; ++r) {
            const int qo = qbase + w * 16 + lhi * 4 + r;
            if (qo < Sb) {
                const size_t orow = (qo == 0) ? (size_t)(N + b) : (size_t)(start + qo - 1);
                const float invl = 1.f / l[r];
                #pragma unroll
                for (int jd = 0; jd < 4; ++jd)
                    out[orow * DM + hh * HDIM + jd * 16 + llo] = f2bf(acc[jd][r] * invl);
            }
        }
    }
}

// ---------------- head ----------------

__global__ __launch_bounds__(256) void head_kernel(const float* __restrict__ h,
                                                   const float* __restrict__ w1,
                                                   const float* __restrict__ b1,
                                                   const float* __restrict__ w2,
                                                   const float* __restrict__ b2,
                                                   float* __restrict__ out, int N) {
    const int b = blockIdx.x;
    const int t = threadIdx.x;
    __shared__ float cls[DM];
    __shared__ float hid[DM];
    cls[t] = h[(size_t)(N + b) * DM + t];
    __syncthreads();
    float s = b1[t];
    for (int k = 0; k < DM; ++k) s = fmaf(cls[k], w1[t * DM + k], s);
    hid[t] = fmaxf(s, 0.f);
    __syncthreads();
    if (t < 2) {
        float o = b2[t];
        for (int k = 0; k < DM; ++k) o = fmaf(hid[k], w2[t * DM + k], o);
        out[b * 2 + t] = o;
    }
}

// ---------------- launch ----------------

extern "C" void kernel_launch(void* const* d_in, const int* in_sizes, int n_in,
                              void* d_out, int out_size, void* d_ws, size_t ws_size,
                              hipStream_t stream) {
    const float* dom_emb   = (const float*)d_in[0];
    const int*   dom_idx   = (const int*)d_in[1];
    const float* geometry  = (const float*)d_in[3];
    const float* in_w      = (const float*)d_in[4];
    const float* in_b      = (const float*)d_in[5];
    const float* geo_w     = (const float*)d_in[6];
    const float* geo_b     = (const float*)d_in[7];
    const float* cls_tok   = (const float*)d_in[8];
    const float* qkv_w     = (const float*)d_in[9];
    const float* qkv_b     = (const float*)d_in[10];
    const float* out_w     = (const float*)d_in[11];
    const float* out_b     = (const float*)d_in[12];
    const float* ln1_w     = (const float*)d_in[13];
    const float* ln1_b     = (const float*)d_in[14];
    const float* ln2_w     = (const float*)d_in[15];
    const float* ln2_b     = (const float*)d_in[16];
    const float* ff_w1     = (const float*)d_in[17];
    const float* ff_b1     = (const float*)d_in[18];
    const float* ff_w2     = (const float*)d_in[19];
    const float* ff_b2     = (const float*)d_in[20];
    const float* head_w1   = (const float*)d_in[21];
    const float* head_b1   = (const float*)d_in[22];
    const float* head_w2   = (const float*)d_in[23];
    const float* head_b2   = (const float*)d_in[24];
    float* outp = (float*)d_out;

    const int N = in_sizes[0] / D_INPUT;       // 65536
    const int T = N + BEV;                     // 65664 = 513 * 128

    // workspace layout (bytes). Total ~208.3 MB.
    char* base = (char*)d_ws;
    size_t off = 0;
    int* counts = (int*)(base + off);          off += 1024;
    int* starts = (int*)(base + off);          off += 1024;
    u16*   Web  = (u16*)(base + off);          off += (size_t)256 * 384 * 2;
    float* be   = (float*)(base + off);        off += 1024;
    u16*   wq   = (u16*)(base + off);          off += (size_t)NLAYERS * 768 * 256 * 2;
    u16*   wo   = (u16*)(base + off);          off += (size_t)NLAYERS * 256 * 256 * 2;
    u16*   w1b  = (u16*)(base + off);          off += (size_t)NLAYERS * 1024 * 256 * 2;
    u16*   w2b  = (u16*)(base + off);          off += (size_t)NLAYERS * 256 * 1024 * 2;
    float* h    = (float*)(base + off);        off += (size_t)T * DM * 4;     // 67.2 MB
    u16*   xb   = (u16*)(base + off);          off += (size_t)T * DM * 2;     // 33.6 MB
    char*  bigc = base + off;                  off += (size_t)T * 768 * 2;    // 100.9 MB
    u16* Ab   = (u16*)bigc;
    u16* qkvb = (u16*)bigc;
    u16* ffm  = (u16*)bigc;

    if (ws_size < off) {
        beacon_kernel<<<1, 256, 0, stream>>>(outp, out_size, (float)(ws_size >> 20));
        return;
    }

    // ---- weight conversion to bf16 ----
    cvt_kernel<<<(NLAYERS * 768 * 256 + 255) / 256, 256, 0, stream>>>(qkv_w, wq, NLAYERS * 768 * 256);
    cvt_kernel<<<(NLAYERS * 256 * 256 + 255) / 256, 256, 0, stream>>>(out_w, wo, NLAYERS * 256 * 256);
    cvt_kernel<<<(NLAYERS * 1024 * 256 + 255) / 256, 256, 0, stream>>>(ff_w1, w1b, NLAYERS * 1024 * 256);
    cvt_kernel<<<(NLAYERS * 256 * 1024 + 255) / 256, 256, 0, stream>>>(ff_w2, w2b, NLAYERS * 256 * 1024);
    prep_w_kernel<<<(256 * 384 + 255) / 256, 256, 0, stream>>>(in_w, geo_w, in_b, geo_b, Web, be);

    // ---- event bookkeeping ----
    zero_counts_kernel<<<1, BEV, 0, stream>>>(counts);
    count_kernel<<<(N + 255) / 256, 256, 0, stream>>>(dom_idx, counts, N);
    scan_kernel<<<1, 64, 0, stream>>>(counts, starts);

    // ---- embed ----
    prep_a_kernel<<<(int)(((size_t)N * 384 + 255) / 256), 256, 0, stream>>>(dom_emb, geometry, Ab, N);
    mgemm_kernel<float><<<dim3(2, N / 128), 256, 0, stream>>>(Ab, Web, be, h, 384, DM, 0);
    cls_kernel<<<BEV, DM, 0, stream>>>(cls_tok, h, N);

    // ---- transformer layers ----
    const int lnGrid = (T + 3) / 4;
    const int CH = 171 * 128;                   // 21888 rows per FF chunk, 3 chunks
    for (int l = 0; l < NLAYERS; ++l) {
        ln_kernel<<<lnGrid, 256, 0, stream>>>(h, ln1_w + l * DM, ln1_b + l * DM, xb, T);
        mgemm_kernel<u16><<<dim3(6, T / 128), 256, 0, stream>>>(
            xb, wq + (size_t)l * 768 * 256, qkv_b + l * 768, qkvb, 256, 768, 0);
        mattn_kernel<<<dim3(BEV * NHEADS, 16), 256, 0, stream>>>(qkvb, counts, starts, xb, N);
        mgemm_kernel<float><<<dim3(2, T / 128), 256, 0, stream>>>(
            xb, wo + (size_t)l * 256 * 256, out_b + l * DM, h, 256, DM, 2);
        ln_kernel<<<lnGrid, 256, 0, stream>>>(h, ln2_w + l * DM, ln2_b + l * DM, xb, T);
        for (int c = 0; c < 3; ++c) {
            const size_t r0 = (size_t)c * CH;
            mgemm_kernel<u16><<<dim3(8, 171), 256, 0, stream>>>(
                xb + r0 * DM, w1b + (size_t)l * DFF * 256, ff_b1 + l * DFF, ffm, 256, DFF, 1);
            mgemm_kernel<float><<<dim3(2, 171), 256, 0, stream>>>(
                ffm, w2b + (size_t)l * 256 * DFF, ff_b2 + l * DM, h + r0 * DM, DFF, DM, 2);
        }
    }

    // ---- head ----
    head_kernel<<<BEV, DM, 0, stream>>>(h, head_w1, head_b1, head_w2, head_b2, outp, N);
}